// Round 14
// baseline (116.220 us; speedup 1.0000x reference)
//
#include <hip/hip_runtime.h>
#include <math.h>

#define PS    65
#define PWP   74                // PW pitch
#define SPIT  36                // ring-row pitch: 4 windows x 9 slots
#define NTH   256
#define QS    1024.0f           // pack scale (global scale cancels in L2 norms)

// atan(t)*(4/pi) for t in [0,1], degree-9 odd minimax, |err|<=1.3e-5
#define C0  1.2730689f
#define C1 -0.4205505f
#define C2  0.2293627f
#define C3 -0.1083947f
#define C4  0.0265281f

// triangular pooling weight, compile-time
__host__ __device__ constexpr float triwc(int t) {
    float d = (float)t - 12.5f;
    d = d < 0.0f ? -d : d;
    return (13.0f - d) / 13.0f;
}

__global__ __launch_bounds__(NTH) void sift_desc_kernel(
        const float* __restrict__ img, float* __restrict__ out) {
    const int s   = blockIdx.x;     // slice index in (B, C, 8, 8) row-major
    const int tid = threadIdx.x;

    // decode slice -> (b, c, tile_i, tile_j)
    const int b   = s / 192;        // C*8*8 = 192
    const int rem = s - b * 192;
    const int c   = rem >> 6;
    const int t2  = rem & 63;
    const int pi  = t2 >> 3;
    const int pj  = t2 & 7;
    const float* src = img + ((size_t)((b * 3 + c) * 520 + pi * 65)) * 520 + pj * 65;

    __shared__ unsigned int PW[PS * PWP];   // 19.2 KB packed (w0,w1,b0), pad cols zero
    __shared__ float S[64 * SPIT + SPIT];   // rings for y=0..63 (+ safety row), 9.4 KB
    __shared__ float QR[16][9];             // row-64 quarter rings
    __shared__ float gtab[PS];              // UNNORMALIZED gaussian (scale cancels)
    __shared__ float fin[128];
    __shared__ float redv[2];

    // phase 0: gaussian; zero PW pad cols (0..5, 71..73); zero rings
    if (tid < PS) {
        float d = (float)(tid - 32);
        gtab[tid] = expf(-(d * d) * (1.0f / 4225.0f));  // sigma=65/sqrt2 -> 2s^2=4225
    }
    for (int k = tid; k < 585; k += NTH) {              // 65 rows x 9 pad cols
        int r = k / 9, cc = k - 9 * r;
        int col = (cc < 6) ? cc : cc + 65;              // 6..8 -> 71..73
        PW[r * PWP + col] = 0u;
    }
    for (int k = tid; k < 65 * SPIT; k += NTH) S[k] = 0.0f;
    if (tid < 144) ((float*)QR)[tid] = 0.0f;
    __syncthreads();

    // ---- pass 1 (FLATTENED, perfectly balanced): thread t handles pixels
    // p in [(4225 t)>>8, (4225(t+1))>>8) -- 16..17 px, no leftover items.
    {
        const int p0 = (4225 * tid) >> 8;
        const int p1 = (4225 * (tid + 1)) >> 8;
        int y  = p0 / 65;
        int x  = p0 - y * 65;
        int ro = y * 520;

        for (int p = p0; p < p1; ++p) {
            const int rm = ro - ((y > 0)  ? 520 : 0);
            const int rp = ro + ((y < 64) ? 520 : 0);
            const int xl = (x > 0)  ? x - 1 : 0;
            const int xr = (x < 64) ? x + 1 : 64;
            float lft = src[ro + xl];
            float rgt = src[ro + xr];
            float top = src[rm + x];
            float bot = src[rp + x];

            float G = rgt - lft;              // 2*gx
            float H = bot - top;              // 2*gy
            float mag = sqrtf(fmaf(G, G, fmaf(H, H, 4e-10f))) * (gtab[y] * gtab[x]);
            float Gx = G + 2e-10f;
            float ax = fabsf(Gx), ay = fabsf(H);
            float mn = fminf(ax, ay), mx = fmaxf(ax, ay);
            float t1 = mn * __builtin_amdgcn_rcpf(fmaxf(mx, 1e-35f));
            float ss = t1 * t1;
            float u9 = t1 * fmaf(ss, fmaf(ss, fmaf(ss, fmaf(ss, C4, C3), C2), C1), C0);
            float A  = (ay > ax) ? 2.0f - u9 : u9;
            A = (Gx < 0.0f) ? 4.0f - A : A;
            A = (H  < 0.0f) ? -A : A;
            float ob = A + 8.0f;              // in [4,12]
            float fl = truncf(ob);
            float fr = ob - fl;
            int b0 = ((int)fl) & 7;
            float w1 = fr * mag;
            float w0 = mag - w1;
            unsigned uq0 = (unsigned)fminf(w0 * QS, 16383.0f);
            unsigned uq1 = (unsigned)fminf(w1 * QS, 16383.0f);
            PW[y * PWP + x + 6] = uq0 | (uq1 << 14) | ((unsigned)b0 << 28);

            ++x;
            const int w = (x == 65) ? 1 : 0;
            y += w;
            ro += w ? 520 : 0;
            x = w ? 0 : x;
        }
    }
    __syncthreads();

    // ---- pass 2: main items (y=0..63, j) = exactly 256 -> one 26-visit ring
    // chain per thread (exclusive 9-slot ring, ds_read2/write2 RMW, no atomics).
    {
        const int y = tid >> 2;
        const int j = tid & 3;
        const unsigned int* pwrow = &PW[y * PWP + (j << 4)];
        float* ring = &S[y * SPIT + j * 9];

        #pragma unroll
        for (int t = 0; t < 26; ++t) {
            const float wq = triwc(t);                 // compile-time
            unsigned u = pwrow[t];
            float q0f = (float)(u & 0x3FFFu);
            float q1f = (float)((u >> 14) & 0x3FFFu);
            int   b0  = (int)(u >> 28);
            ring[b0]     = fmaf(q0f, wq, ring[b0]);
            ring[b0 + 1] = fmaf(q1f, wq, ring[b0 + 1]);
        }
    }
    // row 64: 16 quarter-chains (6-7 visits) on lanes 60..63 of each wave
    if ((tid & 63) >= 60) {
        const int qi = ((tid >> 6) << 2) + (tid & 63) - 60;   // 0..15
        const int j  = qi >> 2;
        const int qq = qi & 3;
        const int t0 = (26 * qq + 3) >> 2;        // {0,7,13,20}
        const int t1 = (26 * (qq + 1) + 3) >> 2;  // {7,13,20,26}
        const unsigned int* pwrow = &PW[64 * PWP + (j << 4)];
        float* ring = QR[qi];
        for (int t = t0; t < t1; ++t) {
            float wq = (13.0f - fabsf((float)t - 12.5f)) * (1.0f / 13.0f);
            unsigned u = pwrow[t];
            float q0f = (float)(u & 0x3FFFu);
            float q1f = (float)((u >> 14) & 0x3FFFu);
            int   b0  = (int)(u >> 28);
            ring[b0]     = fmaf(q0f, wq, ring[b0]);
            ring[b0 + 1] = fmaf(q1f, wq, ring[b0 + 1]);
        }
    }
    __syncthreads();

    // fold ring slot 8 into slot 0 (bin-0 wrap)
    for (int k = tid; k < 260; k += NTH) {
        const int r = k >> 2;
        const int j = k & 3;
        const int o = r * SPIT + j * 9;
        if (r < 64) S[o] += S[o + 8];
    }
    if (tid < 16) QR[tid][0] += QR[tid][8];
    __syncthreads();

    // ---- row pass: bin = k*16 + ii*4 + j; y = 16*ii + t - 6 (0..63 from S,
    // 64 from QR at ii=3,t=22; out-of-range t's weight 0)
    if (tid < 128) {
        const int k  = tid >> 4;
        const int ii = (tid >> 2) & 3;
        const int j  = tid & 3;
        float v = 0.0f;
        #pragma unroll
        for (int t = 0; t < 26; ++t) {
            const int y  = 16 * ii + t - 6;
            const bool ok = (y >= 0) && (y <= 63);
            const int yc = ok ? y : 0;
            const float wy = ok ? triwc(t) : 0.0f;
            v = fmaf(wy, S[yc * SPIT + j * 9 + k], v);
        }
        if (ii == 3) {
            v += triwc(22) * (QR[4*j+0][k] + QR[4*j+1][k] + QR[4*j+2][k] + QR[4*j+3][k]);
        }
        fin[tid] = v;
    }
    __syncthreads();

    // first L2 norm
    if (tid < 64) {
        float sq = fin[tid] * fin[tid] + fin[tid + 64] * fin[tid + 64];
        #pragma unroll
        for (int off = 32; off > 0; off >>= 1) sq += __shfl_down(sq, off);
        if (tid == 0) redv[0] = sq;
    }
    __syncthreads();
    float inv1 = 1.0f / fmaxf(sqrtf(redv[0]), 1e-12f);
    if (tid < 128) {
        fin[tid] = fminf(fin[tid] * inv1, 0.2f);   // non-negative; clip hi only
    }
    __syncthreads();

    // second L2 norm
    if (tid < 64) {
        float sq = fin[tid] * fin[tid] + fin[tid + 64] * fin[tid + 64];
        #pragma unroll
        for (int off = 32; off > 0; off >>= 1) sq += __shfl_down(sq, off);
        if (tid == 0) redv[1] = sq;
    }
    __syncthreads();
    float inv2 = 1.0f / fmaxf(sqrtf(redv[1]), 1e-12f);
    if (tid < 128) {
        out[(size_t)s * 128 + tid] = fin[tid] * inv2;
    }
}

extern "C" void kernel_launch(void* const* d_in, const int* in_sizes, int n_in,
                              void* d_out, int out_size, void* d_ws, size_t ws_size,
                              hipStream_t stream) {
    const float* img = (const float*)d_in[0];
    float* out = (float*)d_out;
    const int B = in_sizes[0] / (3 * 520 * 520);
    const int nslices = B * 192;
    sift_desc_kernel<<<nslices, NTH, 0, stream>>>(img, out);
}

// Round 15
// 72.290 us; speedup vs baseline: 1.6077x; 1.6077x over previous
//
#include <hip/hip_runtime.h>
#include <math.h>

#define PS    65
#define PWP   74                // PW pitch
#define SPIT  36                // ring-row pitch: 4 windows x 9 slots
#define NTH   256
#define QS    1024.0f           // pack scale (global scale cancels in L2 norms)

// atan(t)*(4/pi) for t in [0,1], degree-9 odd minimax, |err|<=1.3e-5
#define C0  1.2730689f
#define C1 -0.4205505f
#define C2  0.2293627f
#define C3 -0.1083947f
#define C4  0.0265281f

// triangular pooling weight, compile-time
__host__ __device__ constexpr float triwc(int t) {
    float d = (float)t - 12.5f;
    d = d < 0.0f ? -d : d;
    return (13.0f - d) / 13.0f;
}

__global__ __launch_bounds__(NTH) void sift_desc_kernel(
        const float* __restrict__ img, float* __restrict__ out) {
    const int s   = blockIdx.x;     // slice index in (B, C, 8, 8) row-major
    const int tid = threadIdx.x;

    // decode slice -> (b, c, tile_i, tile_j)
    const int b   = s / 192;        // C*8*8 = 192
    const int rem = s - b * 192;
    const int c   = rem >> 6;
    const int t2  = rem & 63;
    const int pi  = t2 >> 3;
    const int pj  = t2 & 7;
    const float* src = img + ((size_t)((b * 3 + c) * 520 + pi * 65)) * 520 + pj * 65;

    __shared__ unsigned int PW[PS * PWP];   // 19.2 KB packed (w0,w1,b0), pad cols zero
    __shared__ float S[64 * SPIT + SPIT];   // rings for y=0..63 (+ safety row)
    __shared__ float QR[16][9];             // row-64 quarter rings
    __shared__ float gtab[PS];              // UNNORMALIZED gaussian (scale cancels)
    __shared__ float fin[128];
    __shared__ float redv[2];

    // phase 0: gaussian; zero PW pad cols (0..5, 71..73); zero rings
    if (tid < PS) {
        float d = (float)(tid - 32);
        gtab[tid] = expf(-(d * d) * (1.0f / 4225.0f));  // sigma=65/sqrt2 -> 2s^2=4225
    }
    for (int k = tid; k < 585; k += NTH) {              // 65 rows x 9 pad cols
        int r = k / 9, cc = k - 9 * r;
        int col = (cc < 6) ? cc : cc + 65;              // 6..8 -> 71..73
        PW[r * PWP + col] = 0u;
    }
    for (int k = tid; k < 65 * SPIT; k += NTH) S[k] = 0.0f;
    if (tid < 144) ((float*)QR)[tid] = 0.0f;
    __syncthreads();

#define PX1(CNEXT_EXPR, TOP, BOT, GXT, PWIDX)                                  \
        {                                                                      \
            float cnext = (CNEXT_EXPR);                                        \
            float G = cnext - cprev;          /* 2*gx */                       \
            float H = (BOT) - (TOP);          /* 2*gy */                       \
            float mag = sqrtf(fmaf(G, G, fmaf(H, H, 4e-10f))) * (gy_t * (GXT)); \
            float Gx = G + 2e-10f;                                             \
            float ax = fabsf(Gx), ay = fabsf(H);                               \
            float mn = fminf(ax, ay), mx = fmaxf(ax, ay);                      \
            float t1 = mn * __builtin_amdgcn_rcpf(fmaxf(mx, 1e-35f));          \
            float ss = t1 * t1;                                                \
            float u9 = t1 * fmaf(ss, fmaf(ss, fmaf(ss, fmaf(ss, C4, C3), C2), C1), C0); \
            float A  = (ay > ax) ? 2.0f - u9 : u9;                             \
            A = (Gx < 0.0f) ? 4.0f - A : A;                                    \
            A = (H  < 0.0f) ? -A : A;                                          \
            float ob = A + 8.0f;              /* in [4,12] */                  \
            float fl = truncf(ob);                                             \
            float fr = ob - fl;                                                \
            int b0 = ((int)fl) & 7;                                            \
            float w1 = fr * mag;                                               \
            float w0 = mag - w1;                                               \
            unsigned uq0 = (unsigned)fminf(w0 * QS, 16383.0f);                 \
            unsigned uq1 = (unsigned)fminf(w1 * QS, 16383.0f);                 \
            PW[PWIDX] = uq0 | (uq1 << 14) | ((unsigned)b0 << 28);              \
            cprev = ccur; ccur = cnext;                                        \
        }

    // ---- pass 1 main: item = (y in 0..63, quarter q) = exactly 256, one per
    // thread. Sliding-window body, immediate-offset global reads (L1/L2-served).
    {
        const int y  = tid >> 2;
        const int q  = tid & 3;
        const int x0 = q << 4;

        const float* pc = src + y * 520 + x0;
        const float* pm = src + (y > 0 ? y - 1 : 0) * 520 + x0;
        const float* pp = src + (y + 1) * 520 + x0;    // y<=63: no clamp needed
        const float gy_t = gtab[y];
        const int pwb = y * PWP + 6 + x0;              // store at col x+6

        float cprev = (q == 0) ? pc[0] : pc[-1];
        float ccur  = pc[0];

        #pragma unroll
        for (int i = 0; i < 16; ++i) {
            PX1(pc[i + 1], pm[i], pp[i], gtab[x0 + i], pwb + i)
        }
        if (q == 3) {   // x=64: right neighbor clamps to itself (cnext = ccur)
            PX1(ccur, pm[16], pp[16], gtab[64], pwb + 16)
        }
    }
    // pass 1 tail: row 64, one pixel per thread (threads 0..64) -- wall 18 px not 34
    if (tid < 65) {
        const int x = tid;
        const float* r64 = src + 64 * 520;
        const float* r63 = src + 63 * 520;
        const float gy_t = gtab[64];
        float cprev = r64[(x > 0) ? x - 1 : 0];
        float ccur  = r64[x];
        PX1(r64[(x < 64) ? x + 1 : 64], r63[x], r64[x] /*bot clamps to self*/,
            gtab[x], 64 * PWP + x + 6)
    }
#undef PX1
    __syncthreads();

    // ---- pass 2: main items (y=0..63, j) = exactly 256 -> one 26-visit ring
    // chain per thread (exclusive 9-slot ring, ds_read2/write2 RMW, no atomics).
    {
        const int y = tid >> 2;
        const int j = tid & 3;
        const unsigned int* pwrow = &PW[y * PWP + (j << 4)];
        float* ring = &S[y * SPIT + j * 9];

        #pragma unroll
        for (int t = 0; t < 26; ++t) {
            const float wq = triwc(t);                 // compile-time
            unsigned u = pwrow[t];
            float q0f = (float)(u & 0x3FFFu);
            float q1f = (float)((u >> 14) & 0x3FFFu);
            int   b0  = (int)(u >> 28);
            ring[b0]     = fmaf(q0f, wq, ring[b0]);
            ring[b0 + 1] = fmaf(q1f, wq, ring[b0 + 1]);
        }
    }
    // row 64: 16 quarter-chains (6-7 visits) on lanes 60..63 of each wave
    if ((tid & 63) >= 60) {
        const int qi = ((tid >> 6) << 2) + (tid & 63) - 60;   // 0..15
        const int j  = qi >> 2;
        const int qq = qi & 3;
        const int t0 = (26 * qq + 3) >> 2;        // {0,7,13,20}
        const int t1 = (26 * (qq + 1) + 3) >> 2;  // {7,13,20,26}
        const unsigned int* pwrow = &PW[64 * PWP + (j << 4)];
        float* ring = QR[qi];
        for (int t = t0; t < t1; ++t) {
            float wq = (13.0f - fabsf((float)t - 12.5f)) * (1.0f / 13.0f);
            unsigned u = pwrow[t];
            float q0f = (float)(u & 0x3FFFu);
            float q1f = (float)((u >> 14) & 0x3FFFu);
            int   b0  = (int)(u >> 28);
            ring[b0]     = fmaf(q0f, wq, ring[b0]);
            ring[b0 + 1] = fmaf(q1f, wq, ring[b0 + 1]);
        }
    }
    __syncthreads();

    // fold ring slot 8 into slot 0 (bin-0 wrap)
    for (int k = tid; k < 260; k += NTH) {
        const int r = k >> 2;
        const int j = k & 3;
        const int o = r * SPIT + j * 9;
        if (r < 64) S[o] += S[o + 8];
    }
    if (tid < 16) QR[tid][0] += QR[tid][8];
    __syncthreads();

    // ---- row pass: bin = k*16 + ii*4 + j; y = 16*ii + t - 6 (0..63 from S,
    // 64 from QR at ii=3,t=22; out-of-range t's weight 0)
    if (tid < 128) {
        const int k  = tid >> 4;
        const int ii = (tid >> 2) & 3;
        const int j  = tid & 3;
        float v = 0.0f;
        #pragma unroll
        for (int t = 0; t < 26; ++t) {
            const int y  = 16 * ii + t - 6;
            const bool ok = (y >= 0) && (y <= 63);
            const int yc = ok ? y : 0;
            const float wy = ok ? triwc(t) : 0.0f;
            v = fmaf(wy, S[yc * SPIT + j * 9 + k], v);
        }
        if (ii == 3) {
            v += triwc(22) * (QR[4*j+0][k] + QR[4*j+1][k] + QR[4*j+2][k] + QR[4*j+3][k]);
        }
        fin[tid] = v;
    }
    __syncthreads();

    // first L2 norm
    if (tid < 64) {
        float sq = fin[tid] * fin[tid] + fin[tid + 64] * fin[tid + 64];
        #pragma unroll
        for (int off = 32; off > 0; off >>= 1) sq += __shfl_down(sq, off);
        if (tid == 0) redv[0] = sq;
    }
    __syncthreads();
    float inv1 = 1.0f / fmaxf(sqrtf(redv[0]), 1e-12f);
    if (tid < 128) {
        fin[tid] = fminf(fin[tid] * inv1, 0.2f);   // non-negative; clip hi only
    }
    __syncthreads();

    // second L2 norm
    if (tid < 64) {
        float sq = fin[tid] * fin[tid] + fin[tid + 64] * fin[tid + 64];
        #pragma unroll
        for (int off = 32; off > 0; off >>= 1) sq += __shfl_down(sq, off);
        if (tid == 0) redv[1] = sq;
    }
    __syncthreads();
    float inv2 = 1.0f / fmaxf(sqrtf(redv[1]), 1e-12f);
    if (tid < 128) {
        out[(size_t)s * 128 + tid] = fin[tid] * inv2;
    }
}

extern "C" void kernel_launch(void* const* d_in, const int* in_sizes, int n_in,
                              void* d_out, int out_size, void* d_ws, size_t ws_size,
                              hipStream_t stream) {
    const float* img = (const float*)d_in[0];
    float* out = (float*)d_out;
    const int B = in_sizes[0] / (3 * 520 * 520);
    const int nslices = B * 192;
    sift_desc_kernel<<<nslices, NTH, 0, stream>>>(img, out);
}

// Round 16
// 65.101 us; speedup vs baseline: 1.7852x; 1.1104x over previous
//
#include <hip/hip_runtime.h>
#include <math.h>

#define PS   65
#define NTH  256

// atan(t)*(4/pi) for t in [0,1], degree-9 odd minimax, |err|<=1.3e-5
#define C0  1.2730689f
#define C1 -0.4205505f
#define C2  0.2293627f
#define C3 -0.1083947f
#define C4  0.0265281f

// triangular pooling weight, compile-time
__host__ __device__ constexpr float triwc(int t) {
    float d = (float)t - 12.5f;
    d = d < 0.0f ? -d : d;
    return (13.0f - d) / 13.0f;
}

// per-pixel math -> sarr[8] (w0 at bin b0, w1 at bin b0+1 mod 8)
#define PXS(CN, TP, BT, GXT)                                                   \
    float sarr[8];                                                             \
    {                                                                          \
        float cnext = (CN);                                                    \
        float G = cnext - cprev;            /* 2*gx */                         \
        float H = (BT) - (TP);              /* 2*gy */                         \
        float mag = sqrtf(fmaf(G, G, fmaf(H, H, 4e-10f))) * (gy_t * (GXT));    \
        float Gx = G + 2e-10f;                                                 \
        float ax = fabsf(Gx), ay = fabsf(H);                                   \
        float mn = fminf(ax, ay), mx = fmaxf(ax, ay);                          \
        float t1 = mn * __builtin_amdgcn_rcpf(fmaxf(mx, 1e-35f));              \
        float ss = t1 * t1;                                                    \
        float u9 = t1 * fmaf(ss, fmaf(ss, fmaf(ss, fmaf(ss, C4, C3), C2), C1), C0); \
        float A  = (ay > ax) ? 2.0f - u9 : u9;                                 \
        A = (Gx < 0.0f) ? 4.0f - A : A;                                        \
        A = (H  < 0.0f) ? -A : A;                                              \
        float ob = A + 8.0f;                /* in [4,12] */                    \
        float fl = truncf(ob);                                                 \
        float fr = ob - fl;                                                    \
        int b0 = ((int)fl) & 7;                                                \
        float w1 = fr * mag;                                                   \
        float w0 = mag - w1;                                                   \
        _Pragma("unroll")                                                      \
        for (int k = 0; k < 8; ++k) {                                          \
            const int km1 = (k + 7) & 7;                                       \
            float sv = (b0 == k) ? w0 : 0.0f;                                  \
            sarr[k] = (b0 == km1) ? w1 : sv;                                   \
        }                                                                      \
        cprev = ccur; ccur = cnext;                                            \
    }

__global__ __launch_bounds__(NTH) void sift_desc_kernel(
        const float* __restrict__ img, float* __restrict__ out) {
    const int s   = blockIdx.x;     // slice index in (B, C, 8, 8) row-major
    const int tid = threadIdx.x;

    // decode slice -> (b, c, tile_i, tile_j)
    const int b   = s / 192;        // C*8*8 = 192
    const int rem = s - b * 192;
    const int c   = rem >> 6;
    const int t2  = rem & 63;
    const int pi  = t2 >> 3;
    const int pj  = t2 & 7;
    const float* src = img + ((size_t)((b * 3 + c) * 520 + pi * 65)) * 520 + pj * 65;

    __shared__ __align__(16) float W[260 * 8];  // rows (4y+j) y=0..63; 256..259 = W64[j]
    __shared__ __align__(16) float T[65 * 12];  // row-64 raw sarr, pitch 12 (b128-aligned)
    __shared__ float gtab[PS];                  // UNNORMALIZED gaussian (scale cancels)
    __shared__ float fin[128];
    __shared__ float redv[2];

    if (tid < PS) {
        float d = (float)(tid - 32);
        gtab[tid] = expf(-(d * d) * (1.0f / 4225.0f));  // sigma=65/sqrt2 -> 2s^2=4225
    }
    __syncthreads();

    // ---- fused pass: item = (y in 0..63, quarter q) = exactly 256 threads.
    // All histogram accumulation in registers (24 accs); x-pooling via the
    // per-pixel compile-time window weights; neighbor-window merge via shfl.
    {
        const int y  = tid >> 2;
        const int q  = tid & 3;
        const int x0 = q << 4;

        const float* pc = src + y * 520 + x0;
        const float* pm = src + (y > 0 ? y - 1 : 0) * 520 + x0;
        const float* pp = src + (y + 1) * 520 + x0;    // y<=63: no clamp needed
        const float gy_t = gtab[y];

        float accQ[8] = {0,0,0,0,0,0,0,0};   // window q   (all px,      t=i+6)
        float accB[8] = {0,0,0,0,0,0,0,0};   // window q-1 (px i=0..3,   t=i+22)
        float accP[8] = {0,0,0,0,0,0,0,0};   // window q+1 (px i=10..15, t=i-10)

        float cprev = (q == 0) ? pc[0] : pc[-1];
        float ccur  = pc[0];

        #pragma unroll
        for (int i = 0; i < 16; ++i) {
            PXS(pc[i + 1], pm[i], pp[i], gtab[x0 + i])
            const float WA = triwc(i + 6);
            #pragma unroll
            for (int k = 0; k < 8; ++k) accQ[k] = fmaf(sarr[k], WA, accQ[k]);
            if (i < 4) {
                const float WB = triwc(i + 22);
                #pragma unroll
                for (int k = 0; k < 8; ++k) accB[k] = fmaf(sarr[k], WB, accB[k]);
            }
            if (i >= 10) {
                const float WP = triwc(i - 10);
                #pragma unroll
                for (int k = 0; k < 8; ++k) accP[k] = fmaf(sarr[k], WP, accP[k]);
            }
        }
        if (q == 3) {   // 17th pixel x=64 (t=22, own window only); right clamps to self
            PXS(ccur, pm[16], pp[16], gtab[64])
            const float WA = triwc(22);
            #pragma unroll
            for (int k = 0; k < 8; ++k) accQ[k] = fmaf(sarr[k], WA, accQ[k]);
        }

        // merge neighbor windows via shfl (groups of 4 never straddle a wave)
        const float fB = (q < 3) ? 1.0f : 0.0f;
        const float fP = (q > 0) ? 1.0f : 0.0f;
        float w[8];
        #pragma unroll
        for (int k = 0; k < 8; ++k) {
            float nb = __shfl_down(accB[k], 1);   // from q+1: its window q
            float np = __shfl_up(accP[k], 1);     // from q-1: its window q
            w[k] = accQ[k] + fB * nb + fP * np;
        }
        *(float4*)&W[tid * 8]     = make_float4(w[0], w[1], w[2], w[3]);
        *(float4*)&W[tid * 8 + 4] = make_float4(w[4], w[5], w[6], w[7]);
    }
    // tail: row 64, one pixel per thread (threads 0..64) -> raw sarr into T
    if (tid < PS) {
        const int x = tid;
        const float* r64 = src + 64 * 520;
        const float* r63 = src + 63 * 520;
        const float gy_t = gtab[64];
        float cprev = r64[(x > 0) ? x - 1 : 0];
        float ccur  = r64[x];
        PXS(r64[(x < 64) ? x + 1 : 64], r63[x], r64[x] /*bot clamps to self*/, gtab[x])
        *(float4*)&T[x * 12]     = make_float4(sarr[0], sarr[1], sarr[2], sarr[3]);
        *(float4*)&T[x * 12 + 4] = make_float4(sarr[4], sarr[5], sarr[6], sarr[7]);
    }
    __syncthreads();

    // ---- row pass (tid<128) runs CONCURRENTLY with row-64 x-pooling (tid 128..159)
    const int k  = tid >> 4;          // angular bin   (tid<128)
    const int ii = (tid >> 2) & 3;    // y-window
    const int j  = tid & 3;           // x-window
    float v = 0.0f;
    if (tid < 128) {
        #pragma unroll
        for (int t = 0; t < 26; ++t) {
            const int y  = 16 * ii + t - 6;
            const bool ok = (y >= 0) && (y <= 63);
            const int yc = ok ? y : 0;
            const float wy = ok ? triwc(t) : 0.0f;
            v = fmaf(wy, W[((yc << 2) + j) * 8 + k], v);
        }
    } else if (tid < 160) {
        const int qi = tid - 128;
        const int jj = qi >> 3;       // x-window
        const int kk = qi & 7;        // angular bin
        float w64 = 0.0f;
        #pragma unroll
        for (int t = 0; t < 26; ++t) {
            const int x  = 16 * jj - 6 + t;
            const bool ok = (x >= 0) && (x <= 64);
            const int xc = ok ? x : 0;
            const float wx = ok ? triwc(t) : 0.0f;
            w64 = fmaf(wx, T[xc * 12 + kk], w64);
        }
        W[(256 + jj) * 8 + kk] = w64;
    }
    __syncthreads();

    if (tid < 128) {
        if (ii == 3) v += triwc(22) * W[(256 + j) * 8 + k];  // y=64 term (t=22)
        fin[tid] = v;
    }
    __syncthreads();

    // first L2 norm
    if (tid < 64) {
        float sq = fin[tid] * fin[tid] + fin[tid + 64] * fin[tid + 64];
        #pragma unroll
        for (int off = 32; off > 0; off >>= 1) sq += __shfl_down(sq, off);
        if (tid == 0) redv[0] = sq;
    }
    __syncthreads();
    float inv1 = 1.0f / fmaxf(sqrtf(redv[0]), 1e-12f);
    if (tid < 128) {
        fin[tid] = fminf(fin[tid] * inv1, 0.2f);   // non-negative; clip hi only
    }
    __syncthreads();

    // second L2 norm
    if (tid < 64) {
        float sq = fin[tid] * fin[tid] + fin[tid + 64] * fin[tid + 64];
        #pragma unroll
        for (int off = 32; off > 0; off >>= 1) sq += __shfl_down(sq, off);
        if (tid == 0) redv[1] = sq;
    }
    __syncthreads();
    float inv2 = 1.0f / fmaxf(sqrtf(redv[1]), 1e-12f);
    if (tid < 128) {
        out[(size_t)s * 128 + tid] = fin[tid] * inv2;
    }
}

extern "C" void kernel_launch(void* const* d_in, const int* in_sizes, int n_in,
                              void* d_out, int out_size, void* d_ws, size_t ws_size,
                              hipStream_t stream) {
    const float* img = (const float*)d_in[0];
    float* out = (float*)d_out;
    const int B = in_sizes[0] / (3 * 520 * 520);
    const int nslices = B * 192;
    sift_desc_kernel<<<nslices, NTH, 0, stream>>>(img, out);
}

// Round 17
// 63.431 us; speedup vs baseline: 1.8322x; 1.0263x over previous
//
#include <hip/hip_runtime.h>
#include <math.h>

#define PS   65
#define NTH  256

typedef __attribute__((ext_vector_type(2))) float f32x2;
#define FMA2(a, b, c) __builtin_elementwise_fma((a), (b), (c))

// atan(t)*(4/pi) for t in [0,1], degree-9 odd minimax, |err|<=1.3e-5
#define C0  1.2730689f
#define C1 -0.4205505f
#define C2  0.2293627f
#define C3 -0.1083947f
#define C4  0.0265281f

// triangular pooling weight, compile-time
__host__ __device__ constexpr float triwc(int t) {
    float d = (float)t - 12.5f;
    d = d < 0.0f ? -d : d;
    return (13.0f - d) / 13.0f;
}

// per-pixel math -> sarr2[4] (f32x2 per bin pair; bins 2p,2p+1).
// NOTE: gy_t factored OUT (applied once after merge).
#define PXS(CN, TP, BT, GXT)                                                   \
    f32x2 sarr2[4];                                                            \
    {                                                                          \
        float cnext = (CN);                                                    \
        float G = cnext - cprev;            /* 2*gx */                         \
        float H = (BT) - (TP);              /* 2*gy */                         \
        float mag = sqrtf(fmaf(G, G, fmaf(H, H, 4e-10f))) * (GXT);             \
        float ax = fabsf(G), ay = fabsf(H);                                    \
        float mn = fminf(ax, ay), mx = fmaxf(ax, ay);                          \
        float t1 = mn * __builtin_amdgcn_rcpf(fmaxf(mx, 1e-35f));              \
        float ss = t1 * t1;                                                    \
        float u9 = t1 * fmaf(ss, fmaf(ss, fmaf(ss, fmaf(ss, C4, C3), C2), C1), C0); \
        float A  = (ay > ax) ? 2.0f - u9 : u9;                                 \
        A = (G < 0.0f) ? 4.0f - A : A;                                         \
        A = (H < 0.0f) ? -A : A;                                               \
        float ob = A + 8.0f;                /* in [4,12] */                    \
        float fl = truncf(ob);                                                 \
        float fr = ob - fl;                                                    \
        int b0 = ((int)fl) & 7;                                                \
        float w1 = fr * mag;                                                   \
        float w0 = mag - w1;                                                   \
        _Pragma("unroll")                                                      \
        for (int p = 0; p < 4; ++p) {                                          \
            const int lo = 2 * p, hi = 2 * p + 1, lom1 = (2 * p + 7) & 7;      \
            float sv = (b0 == lo) ? w0 : 0.0f;                                 \
            sarr2[p].x = (b0 == lom1) ? w1 : sv;                               \
            float sv2 = (b0 == hi) ? w0 : 0.0f;                                \
            sarr2[p].y = (b0 == lo) ? w1 : sv2;                                \
        }                                                                      \
        cprev = ccur; ccur = cnext;                                            \
    }

__global__ __launch_bounds__(NTH) void sift_desc_kernel(
        const float* __restrict__ img, float* __restrict__ out) {
    const int s   = blockIdx.x;     // slice index in (B, C, 8, 8) row-major
    const int tid = threadIdx.x;

    // decode slice -> (b, c, tile_i, tile_j)
    const int b   = s / 192;        // C*8*8 = 192
    const int rem = s - b * 192;
    const int c   = rem >> 6;
    const int t2  = rem & 63;
    const int pi  = t2 >> 3;
    const int pj  = t2 & 7;
    const float* src = img + ((size_t)((b * 3 + c) * 520 + pi * 65)) * 520 + pj * 65;

    __shared__ __align__(16) float W[260 * 8];  // rows (4y+j) y=0..63; 256..259 = W64[j]
    __shared__ __align__(16) float T[65 * 12];  // row-64 sarr*gy, pitch 12 (b128-aligned)
    __shared__ __align__(16) float gtab[PS];    // UNNORMALIZED gaussian (scale cancels)
    __shared__ float fin[128];
    __shared__ float redv[2];

    if (tid < PS) {
        float d = (float)(tid - 32);
        gtab[tid] = expf(-(d * d) * (1.0f / 4225.0f));  // sigma=65/sqrt2 -> 2s^2=4225
    }
    __syncthreads();

    // ---- fused pass: item = (y in 0..63, quarter q) = exactly 256 threads.
    // Register histograms as 4x f32x2 per window (pk-fma accumulate);
    // gtab segment pre-loaded to registers; gy_t applied once after merge.
    {
        const int y  = tid >> 2;
        const int q  = tid & 3;
        const int x0 = q << 4;

        const float* pc = src + y * 520 + x0;
        const float* pm = src + (y > 0 ? y - 1 : 0) * 520 + x0;
        const float* pp = src + (y + 1) * 520 + x0;    // y<=63: no clamp needed
        const float gy_t = gtab[y];

        const float4 Gv0 = *(const float4*)&gtab[x0];
        const float4 Gv1 = *(const float4*)&gtab[x0 + 4];
        const float4 Gv2 = *(const float4*)&gtab[x0 + 8];
        const float4 Gv3 = *(const float4*)&gtab[x0 + 12];
        const float g16  = gtab[x0 + 16];
        const float ga[17] = {Gv0.x, Gv0.y, Gv0.z, Gv0.w, Gv1.x, Gv1.y, Gv1.z, Gv1.w,
                              Gv2.x, Gv2.y, Gv2.z, Gv2.w, Gv3.x, Gv3.y, Gv3.z, Gv3.w, g16};

        f32x2 accQ[4] = {{0,0},{0,0},{0,0},{0,0}};   // window q   (all px,      t=i+6)
        f32x2 accB[4] = {{0,0},{0,0},{0,0},{0,0}};   // window q-1 (px i=0..3,   t=i+22)
        f32x2 accP[4] = {{0,0},{0,0},{0,0},{0,0}};   // window q+1 (px i=10..15, t=i-10)

        float cprev = (q == 0) ? pc[0] : pc[-1];
        float ccur  = pc[0];

        #pragma unroll
        for (int i = 0; i < 16; ++i) {
            PXS(pc[i + 1], pm[i], pp[i], ga[i])
            const f32x2 WA = {triwc(i + 6), triwc(i + 6)};
            #pragma unroll
            for (int p = 0; p < 4; ++p) accQ[p] = FMA2(sarr2[p], WA, accQ[p]);
            if (i < 4) {
                const f32x2 WB = {triwc(i + 22), triwc(i + 22)};
                #pragma unroll
                for (int p = 0; p < 4; ++p) accB[p] = FMA2(sarr2[p], WB, accB[p]);
            }
            if (i >= 10) {
                const f32x2 WP = {triwc(i - 10), triwc(i - 10)};
                #pragma unroll
                for (int p = 0; p < 4; ++p) accP[p] = FMA2(sarr2[p], WP, accP[p]);
            }
        }
        if (q == 3) {   // 17th pixel x=64 (t=22, own window only); right clamps to self
            PXS(ccur, pm[16], pp[16], ga[16])
            const f32x2 WA = {triwc(22), triwc(22)};
            #pragma unroll
            for (int p = 0; p < 4; ++p) accQ[p] = FMA2(sarr2[p], WA, accQ[p]);
        }

        // merge neighbor windows via shfl (groups of 4 never straddle a wave);
        // apply gy_t ONCE here (all merged lanes share the same y).
        const float fB = (q < 3) ? 1.0f : 0.0f;
        const float fP = (q > 0) ? 1.0f : 0.0f;
        float w[8];
        #pragma unroll
        for (int k = 0; k < 8; ++k) {
            const float aq = accQ[k >> 1][k & 1];
            const float ab = accB[k >> 1][k & 1];
            const float ap = accP[k >> 1][k & 1];
            float nb = __shfl_down(ab, 1);   // from q+1: its window q
            float np = __shfl_up(ap, 1);     // from q-1: its window q
            w[k] = (aq + fB * nb + fP * np) * gy_t;
        }
        *(float4*)&W[tid * 8]     = make_float4(w[0], w[1], w[2], w[3]);
        *(float4*)&W[tid * 8 + 4] = make_float4(w[4], w[5], w[6], w[7]);
    }
    // tail: row 64, one pixel per thread (threads 0..64) -> sarr*gy into T
    if (tid < PS) {
        const int x = tid;
        const float* r64 = src + 64 * 520;
        const float* r63 = src + 63 * 520;
        const float gy_t = gtab[64];
        float cprev = r64[(x > 0) ? x - 1 : 0];
        float ccur  = r64[x];
        PXS(r64[(x < 64) ? x + 1 : 64], r63[x], r64[x] /*bot clamps to self*/, gtab[x])
        *(float4*)&T[x * 12]     = make_float4(sarr2[0].x * gy_t, sarr2[0].y * gy_t,
                                               sarr2[1].x * gy_t, sarr2[1].y * gy_t);
        *(float4*)&T[x * 12 + 4] = make_float4(sarr2[2].x * gy_t, sarr2[2].y * gy_t,
                                               sarr2[3].x * gy_t, sarr2[3].y * gy_t);
    }
    __syncthreads();

    // ---- row pass (tid<128) runs CONCURRENTLY with row-64 x-pooling (tid 128..159)
    const int k  = tid >> 4;          // angular bin   (tid<128)
    const int ii = (tid >> 2) & 3;    // y-window
    const int j  = tid & 3;           // x-window
    float v = 0.0f;
    if (tid < 128) {
        #pragma unroll
        for (int t = 0; t < 26; ++t) {
            const int y  = 16 * ii + t - 6;
            const bool ok = (y >= 0) && (y <= 63);
            const int yc = ok ? y : 0;
            const float wy = ok ? triwc(t) : 0.0f;
            v = fmaf(wy, W[((yc << 2) + j) * 8 + k], v);
        }
    } else if (tid < 160) {
        const int qi = tid - 128;
        const int jj = qi >> 3;       // x-window
        const int kk = qi & 7;        // angular bin
        float w64 = 0.0f;
        #pragma unroll
        for (int t = 0; t < 26; ++t) {
            const int x  = 16 * jj - 6 + t;
            const bool ok = (x >= 0) && (x <= 64);
            const int xc = ok ? x : 0;
            const float wx = ok ? triwc(t) : 0.0f;
            w64 = fmaf(wx, T[xc * 12 + kk], w64);
        }
        W[(256 + jj) * 8 + kk] = w64;
    }
    __syncthreads();

    if (tid < 128) {
        if (ii == 3) v += triwc(22) * W[(256 + j) * 8 + k];  // y=64 term (t=22)
        fin[tid] = v;
    }
    __syncthreads();

    // first L2 norm
    if (tid < 64) {
        float sq = fin[tid] * fin[tid] + fin[tid + 64] * fin[tid + 64];
        #pragma unroll
        for (int off = 32; off > 0; off >>= 1) sq += __shfl_down(sq, off);
        if (tid == 0) redv[0] = sq;
    }
    __syncthreads();
    float inv1 = 1.0f / fmaxf(sqrtf(redv[0]), 1e-12f);
    if (tid < 128) {
        fin[tid] = fminf(fin[tid] * inv1, 0.2f);   // non-negative; clip hi only
    }
    __syncthreads();

    // second L2 norm
    if (tid < 64) {
        float sq = fin[tid] * fin[tid] + fin[tid + 64] * fin[tid + 64];
        #pragma unroll
        for (int off = 32; off > 0; off >>= 1) sq += __shfl_down(sq, off);
        if (tid == 0) redv[1] = sq;
    }
    __syncthreads();
    float inv2 = 1.0f / fmaxf(sqrtf(redv[1]), 1e-12f);
    if (tid < 128) {
        out[(size_t)s * 128 + tid] = fin[tid] * inv2;
    }
}

extern "C" void kernel_launch(void* const* d_in, const int* in_sizes, int n_in,
                              void* d_out, int out_size, void* d_ws, size_t ws_size,
                              hipStream_t stream) {
    const float* img = (const float*)d_in[0];
    float* out = (float*)d_out;
    const int B = in_sizes[0] / (3 * 520 * 520);
    const int nslices = B * 192;
    sift_desc_kernel<<<nslices, NTH, 0, stream>>>(img, out);
}

// Round 18
// 61.380 us; speedup vs baseline: 1.8935x; 1.0334x over previous
//
#include <hip/hip_runtime.h>
#include <math.h>

#define PS   65
#define NTH  256

typedef __attribute__((ext_vector_type(2))) float f32x2;
#define FMA2(a, b, c) __builtin_elementwise_fma((a), (b), (c))

// atan(t)*(4/pi) for t in [0,1], degree-9 odd minimax, |err|<=1.3e-5
#define C0  1.2730689f
#define C1 -0.4205505f
#define C2  0.2293627f
#define C3 -0.1083947f
#define C4  0.0265281f

// triangular pooling weight, compile-time
__host__ __device__ constexpr float triwc(int t) {
    float d = (float)t - 12.5f;
    d = d < 0.0f ? -d : d;
    return (13.0f - d) / 13.0f;
}

// per-pixel math -> sarr2[4] (f32x2 per bin pair; bins 2p,2p+1).
// gy_t factored OUT (applied once after merge / at tail store).
#define PXS(CN, TP, BT, GXT)                                                   \
    f32x2 sarr2[4];                                                            \
    {                                                                          \
        float cnext = (CN);                                                    \
        float G = cnext - cprev;            /* 2*gx */                         \
        float H = (BT) - (TP);              /* 2*gy */                         \
        float mag = sqrtf(fmaf(G, G, fmaf(H, H, 4e-10f))) * (GXT);             \
        float ax = fabsf(G), ay = fabsf(H);                                    \
        float mn = fminf(ax, ay), mx = fmaxf(ax, ay);                          \
        float t1 = mn * __builtin_amdgcn_rcpf(fmaxf(mx, 1e-35f));              \
        float ss = t1 * t1;                                                    \
        float u9 = t1 * fmaf(ss, fmaf(ss, fmaf(ss, fmaf(ss, C4, C3), C2), C1), C0); \
        float A  = (ay > ax) ? 2.0f - u9 : u9;                                 \
        A = (G < 0.0f) ? 4.0f - A : A;                                         \
        A = copysignf(A, H);                /* v_bfi: sign of H onto A>=0 */   \
        float ob = A + 8.0f;                /* in [4,12] */                    \
        float fr = ob - floorf(ob);         /* v_fract */                      \
        int b0 = ((int)ob) & 7;                                                \
        float w1 = fr * mag;                                                   \
        float w0 = mag - w1;                                                   \
        _Pragma("unroll")                                                      \
        for (int p = 0; p < 4; ++p) {                                          \
            const int lo = 2 * p, hi = 2 * p + 1, lom1 = (2 * p + 7) & 7;      \
            float sv = (b0 == lo) ? w0 : 0.0f;                                 \
            sarr2[p].x = (b0 == lom1) ? w1 : sv;                               \
            float sv2 = (b0 == hi) ? w0 : 0.0f;                                \
            sarr2[p].y = (b0 == lo) ? w1 : sv2;                                \
        }                                                                      \
        cprev = ccur; ccur = cnext;                                            \
    }

__global__ __launch_bounds__(NTH) void sift_desc_kernel(
        const float* __restrict__ img, float* __restrict__ out) {
    const int s   = blockIdx.x;     // slice index in (B, C, 8, 8) row-major
    const int tid = threadIdx.x;

    // decode slice -> (b, c, tile_i, tile_j)
    const int b   = s / 192;        // C*8*8 = 192
    const int rem = s - b * 192;
    const int c   = rem >> 6;
    const int t2  = rem & 63;
    const int pi  = t2 >> 3;
    const int pj  = t2 & 7;
    const float* src = img + ((size_t)((b * 3 + c) * 520 + pi * 65)) * 520 + pj * 65;

    // W2 rows ry = y+6 for y in [-6,69]; rows 0..5 and 70..75 are zero pads.
    __shared__ __align__(16) float W2[76 * 4 * 8];   // 9.5 KB
    __shared__ __align__(16) float Wc2[76 * 8];      // col-64 (pre-* gy*triwc22), padded
    __shared__ __align__(16) float T[65 * 12];       // row-64 sarr*gy, pitch 12
    __shared__ __align__(16) float W64[4 * 8];       // row-64 x-pooled
    __shared__ float Vc[32];                         // col-64 y-pooled (ii,k)
    __shared__ float gtab[PS];                       // UNNORMALIZED gaussian
    __shared__ float fin[128];
    __shared__ float redv[2];

    if (tid < PS) {
        float d = (float)(tid - 32);
        gtab[tid] = expf(-(d * d) * (1.0f / 4225.0f));  // sigma=65/sqrt2 -> 2s^2=4225
    }
    // zero pad rows of W2 (12 rows x 32) and Wc2 (12 rows x 8)
    for (int kz = tid; kz < 480; kz += NTH) {
        if (kz < 384) {
            int r = kz >> 5;
            int rr = (r < 6) ? r : r + 64;            // 0..5, 70..75
            W2[rr * 32 + (kz & 31)] = 0.0f;
        } else {
            int z = kz - 384;
            int r = z >> 3;
            int rr = (r < 6) ? r : r + 64;
            Wc2[rr * 8 + (z & 7)] = 0.0f;
        }
    }
    __syncthreads();

    // ---- phase A: uniform 16-px main body, all 256 threads (y=0..63, q=0..3)
    {
        const int y  = tid >> 2;
        const int q  = tid & 3;
        const int x0 = q << 4;

        const float* pc = src + y * 520 + x0;
        const float* pm = src + (y > 0 ? y - 1 : 0) * 520 + x0;
        const float* pp = src + (y + 1) * 520 + x0;    // y<=63: no clamp needed
        const float gy_t = gtab[y];

        const float4 Gv0 = *(const float4*)&gtab[x0];
        const float4 Gv1 = *(const float4*)&gtab[x0 + 4];
        const float4 Gv2 = *(const float4*)&gtab[x0 + 8];
        const float4 Gv3 = *(const float4*)&gtab[x0 + 12];
        const float ga[16] = {Gv0.x, Gv0.y, Gv0.z, Gv0.w, Gv1.x, Gv1.y, Gv1.z, Gv1.w,
                              Gv2.x, Gv2.y, Gv2.z, Gv2.w, Gv3.x, Gv3.y, Gv3.z, Gv3.w};

        f32x2 accQ[4] = {{0,0},{0,0},{0,0},{0,0}};   // window q   (all px,      t=i+6)
        f32x2 accB[4] = {{0,0},{0,0},{0,0},{0,0}};   // window q-1 (px i=0..3,   t=i+22)
        f32x2 accP[4] = {{0,0},{0,0},{0,0},{0,0}};   // window q+1 (px i=10..15, t=i-10)

        float cprev = (q == 0) ? pc[0] : pc[-1];
        float ccur  = pc[0];

        #pragma unroll
        for (int i = 0; i < 16; ++i) {
            PXS(pc[i + 1], pm[i], pp[i], ga[i])
            const f32x2 WA = {triwc(i + 6), triwc(i + 6)};
            #pragma unroll
            for (int p = 0; p < 4; ++p) accQ[p] = FMA2(sarr2[p], WA, accQ[p]);
            if (i < 4) {
                const f32x2 WB = {triwc(i + 22), triwc(i + 22)};
                #pragma unroll
                for (int p = 0; p < 4; ++p) accB[p] = FMA2(sarr2[p], WB, accB[p]);
            }
            if (i >= 10) {
                const f32x2 WP = {triwc(i - 10), triwc(i - 10)};
                #pragma unroll
                for (int p = 0; p < 4; ++p) accP[p] = FMA2(sarr2[p], WP, accP[p]);
            }
        }

        // merge neighbor windows via shfl (groups of 4 never straddle a wave);
        // apply gy_t once (merged lanes share y).
        const float fB = (q < 3) ? 1.0f : 0.0f;
        const float fP = (q > 0) ? 1.0f : 0.0f;
        float w[8];
        #pragma unroll
        for (int k = 0; k < 8; ++k) {
            const float aq = accQ[k >> 1][k & 1];
            const float ab = accB[k >> 1][k & 1];
            const float ap = accP[k >> 1][k & 1];
            float nb = __shfl_down(ab, 1);   // from q+1: its window q
            float np = __shfl_up(ap, 1);     // from q-1: its window q
            w[k] = (aq + fB * nb + fP * np) * gy_t;
        }
        float* wb = &W2[(((y + 6) << 2) + q) << 3];
        *(float4*)&wb[0] = make_float4(w[0], w[1], w[2], w[3]);
        *(float4*)&wb[4] = make_float4(w[4], w[5], w[6], w[7]);
    }

    // ---- phase A tails: boundary pixels (threads 0..128), one pixel each
    if (tid < PS) {
        // row 64, x = tid: raw sarr*gy into T (x-pooled in phase B)
        const int x = tid;
        const float* r64 = src + 64 * 520;
        const float* r63 = src + 63 * 520;
        float cprev = r64[(x > 0) ? x - 1 : 0];
        float ccur  = r64[x];
        const float gy_t = gtab[64];
        PXS(r64[(x < 64) ? x + 1 : 64], r63[x], r64[x] /*bot clamps*/, gtab[x])
        *(float4*)&T[x * 12]     = make_float4(sarr2[0].x * gy_t, sarr2[0].y * gy_t,
                                               sarr2[1].x * gy_t, sarr2[1].y * gy_t);
        *(float4*)&T[x * 12 + 4] = make_float4(sarr2[2].x * gy_t, sarr2[2].y * gy_t,
                                               sarr2[3].x * gy_t, sarr2[3].y * gy_t);
    } else if (tid < 129) {
        // col 64, y = tid-65 in [0,63]: only window j=3, wx = triwc(22)
        const int y = tid - 65;
        const float* pr = src + y * 520;
        float cprev = pr[63];
        float ccur  = pr[64];
        const float gw = gtab[y] * triwc(22);   // fold gy * wx
        PXS(ccur /*right clamps*/, src[(y > 0 ? y - 1 : 0) * 520 + 64],
            pr[520 + 64], gtab[64])
        float* cb = &Wc2[(y + 6) * 8];
        *(float4*)&cb[0] = make_float4(sarr2[0].x * gw, sarr2[0].y * gw,
                                       sarr2[1].x * gw, sarr2[1].y * gw);
        *(float4*)&cb[4] = make_float4(sarr2[2].x * gw, sarr2[2].y * gw,
                                       sarr2[3].x * gw, sarr2[3].y * gw);
    }
    __syncthreads();

    // ---- phase B: row pass (tid<128) || row-64 x-pool (128..159) || col-64
    // y-pool (160..191). Padded W2/Wc2 -> no bounds logic in hot loops.
    const int k  = tid >> 4;          // angular bin   (tid<128)
    const int ii = (tid >> 2) & 3;    // y-window
    const int j  = tid & 3;           // x-window
    float v = 0.0f;
    if (tid < 128) {
        #pragma unroll
        for (int t = 0; t < 26; ++t) {
            const int ry = 16 * ii + t;          // 0..73 (rows 70..73 zero)
            v = fmaf(triwc(t), W2[((ry << 2) + j) * 8 + k], v);
        }
    } else if (tid < 160) {
        const int qi = tid - 128;
        const int jj = qi >> 3;       // x-window
        const int kk = qi & 7;        // angular bin
        float w64 = 0.0f;
        #pragma unroll
        for (int t = 0; t < 26; ++t) {
            const int x  = 16 * jj - 6 + t;
            const bool ok = (x >= 0) && (x <= 64);
            const int xc = ok ? x : 0;
            const float wx = ok ? triwc(t) : 0.0f;
            w64 = fmaf(wx, T[xc * 12 + kk], w64);
        }
        W64[jj * 8 + kk] = w64;
    } else if (tid < 192) {
        const int qi = tid - 160;
        const int iw = qi >> 3;       // y-window
        const int kk = qi & 7;        // angular bin
        float sc = 0.0f;
        #pragma unroll
        for (int t = 0; t < 26; ++t) {
            const int ry = 16 * iw + t;          // padded: no bounds
            sc = fmaf(triwc(t), Wc2[ry * 8 + kk], sc);
        }
        Vc[qi] = sc;
    }
    __syncthreads();

    if (tid < 128) {
        if (ii == 3) v += triwc(22) * W64[j * 8 + k];   // y=64 row (t=22)
        v += (j == 3) ? Vc[ii * 8 + k] : 0.0f;          // x=64 column
        fin[tid] = v;
    }
    __syncthreads();

    // first L2 norm
    if (tid < 64) {
        float sq = fin[tid] * fin[tid] + fin[tid + 64] * fin[tid + 64];
        #pragma unroll
        for (int off = 32; off > 0; off >>= 1) sq += __shfl_down(sq, off);
        if (tid == 0) redv[0] = sq;
    }
    __syncthreads();
    float inv1 = 1.0f / fmaxf(sqrtf(redv[0]), 1e-12f);
    if (tid < 128) {
        fin[tid] = fminf(fin[tid] * inv1, 0.2f);   // non-negative; clip hi only
    }
    __syncthreads();

    // second L2 norm
    if (tid < 64) {
        float sq = fin[tid] * fin[tid] + fin[tid + 64] * fin[tid + 64];
        #pragma unroll
        for (int off = 32; off > 0; off >>= 1) sq += __shfl_down(sq, off);
        if (tid == 0) redv[1] = sq;
    }
    __syncthreads();
    float inv2 = 1.0f / fmaxf(sqrtf(redv[1]), 1e-12f);
    if (tid < 128) {
        out[(size_t)s * 128 + tid] = fin[tid] * inv2;
    }
}

extern "C" void kernel_launch(void* const* d_in, const int* in_sizes, int n_in,
                              void* d_out, int out_size, void* d_ws, size_t ws_size,
                              hipStream_t stream) {
    const float* img = (const float*)d_in[0];
    float* out = (float*)d_out;
    const int B = in_sizes[0] / (3 * 520 * 520);
    const int nslices = B * 192;
    sift_desc_kernel<<<nslices, NTH, 0, stream>>>(img, out);
}